// Round 8
// baseline (245.235 us; speedup 1.0000x reference)
//
#include <hip/hip_runtime.h>

#define VOXELS   884736      // 96^3
#define OUT_CAM  0
#define OUT_PSE  23003136    // 2*13*VOXELS
#define OUT_MSK  24772608
#define OUT_LOG  26542080

// ws layout (floats)
#define WS_WT 0              // wt2[27][128][256]  (884736)
#define WS_P  884736         // P[54][2][128][64]  (884736)
#define WS_H1 1769472        // h1[2][128][8]      (2048)

typedef float  f32x4 __attribute__((ext_vector_type(4)));
typedef int    i32x4 __attribute__((ext_vector_type(4)));

// ---------------- CAM + pseudo + updated masks (memory-bound) ----------------
// The 14 loads are forced live simultaneously via a single asm with all values
// as "+v" operands (data dependency -> cannot be sunk by any pass). This gives
// 14 loads in flight per wave instead of the round-1..4 codegen (VGPR=32, one
// load->wait->store round trip at a time, 2.5 TB/s).
__global__ __launch_bounds__(256, 4) void k_cam(const float* __restrict__ feat,
                                                const int*   __restrict__ masks,
                                                float* __restrict__ out) {
  int bx = blockIdx.x;                 // 1728 blocks: 864 per n
  int n  = bx >= 864;
  int q  = (bx - n * 864) * 256 + threadIdx.x;   // quad index < 221184
  int v  = q * 4;
  const float scale = 1.0f / 884736.0f;

  f32x4 f[13];
#pragma unroll
  for (int k = 0; k < 13; ++k)
    f[k] = *(const f32x4*)(feat + (size_t)(n * 14 + 1 + k) * VOXELS + v);
  i32x4 m = *(const i32x4*)(masks + (size_t)n * VOXELS + v);
  // force all 14 loads to be issued before any consumer
  asm volatile(""
               : "+v"(f[0]), "+v"(f[1]), "+v"(f[2]), "+v"(f[3]), "+v"(f[4]),
                 "+v"(f[5]), "+v"(f[6]), "+v"(f[7]), "+v"(f[8]), "+v"(f[9]),
                 "+v"(f[10]), "+v"(f[11]), "+v"(f[12]), "+v"(m));

  f32x4 best = {0, 0, 0, 0};
  i32x4 bi = {0, 0, 0, 0};
#pragma unroll
  for (int k = 0; k < 13; ++k) {
    f32x4 t = f[k] * scale;
    t.x = (t.x > 0.2f) ? t.x : 0.0f;
    t.y = (t.y > 0.2f) ? t.y : 0.0f;
    t.z = (t.z > 0.2f) ? t.z : 0.0f;
    t.w = (t.w > 0.2f) ? t.w : 0.0f;
    __builtin_nontemporal_store(t, (f32x4*)(out + OUT_CAM + (size_t)(n * 13 + k) * VOXELS + v));
    if (k == 0) {
      best = t;
    } else {
      if (t.x > best.x) { best.x = t.x; bi.x = k; }
      if (t.y > best.y) { best.y = t.y; bi.y = k; }
      if (t.z > best.z) { best.z = t.z; bi.z = k; }
      if (t.w > best.w) { best.w = t.w; bi.w = k; }
    }
  }
  f32x4 ps = {(float)bi.x, (float)bi.y, (float)bi.z, (float)bi.w};
  f32x4 um;
  um.x = (m.x == 0) ? ps.x : (float)m.x;
  um.y = (m.y == 0) ? ps.y : (float)m.y;
  um.z = (m.z == 0) ? ps.z : (float)m.z;
  um.w = (m.w == 0) ? ps.w : (float)m.w;
  __builtin_nontemporal_store(ps, (f32x4*)(out + OUT_PSE + (size_t)n * VOXELS + v));
  __builtin_nontemporal_store(um, (f32x4*)(out + OUT_MSK + (size_t)n * VOXELS + v));
}

// ---------------- coalesced transpose: wt2[tap][oc][ic] = w1[oc][ic][tap] ----------------
// view w1 as A[r=(oc,ic)][tap]: rows contiguous -> tile = contiguous 6912-float read
// (staged as 1728 float4 loads, ~7 independent per thread). Also zeroes logits.
__global__ __launch_bounds__(256) void k_trans(const float* __restrict__ w1,
                                               float* __restrict__ wt,
                                               float* __restrict__ logits) {
  __shared__ float s[6912];
  int r0 = blockIdx.x * 256;
  int tid = threadIdx.x;
  if (blockIdx.x == 0 && tid < 2) logits[tid] = 0.0f;
  for (int i = tid; i < 1728; i += 256)
    *(f32x4*)&s[i * 4] = *(const f32x4*)&w1[(size_t)r0 * 27 + i * 4];
  __syncthreads();
#pragma unroll
  for (int tap = 0; tap < 27; ++tap)
    wt[tap * 32768 + r0 + tid] = s[tid * 27 + tap];   // stride 27 coprime 32 banks
}

// ---------------- conv1 split-K partial GEMMs ----------------
// grid 216 = 2n * 27tap * 2ich * 2och ; block computes 64oc x 64pos over 128 ic
#define WSTRIDE 68
__global__ __launch_bounds__(256) void k_conv1(const float* __restrict__ dom,
                                               const float* __restrict__ wt,
                                               float* __restrict__ P) {
  __shared__ float Wl[128 * WSTRIDE];   // [kk][oc'] padded: +4 rotates banks
  __shared__ float Xl[128 * 64];        // [kk][pos]
  int bx = blockIdx.x;
  int och = bx & 1;
  int ich = (bx >> 1) & 1;
  int rest = bx >> 2;              // 0..53
  int tap = rest % 27;
  int n = rest / 27;
  int kd = tap / 9 - 1, kh = (tap % 9) / 3 - 1, kw = tap % 3 - 1;
  int I0 = ich * 128, O0 = och * 64;
  int tid = threadIdx.x;

  // stage W: read wt2[tap][oc][ic] coalesced (float4 over ic), transpose into LDS
  for (int i = tid; i < 2048; i += 256) {
    int oc = i >> 5, k4 = (i & 31) << 2;
    f32x4 rd = *(const f32x4*)&wt[(size_t)(tap * 128 + O0 + oc) * 256 + I0 + k4];
    Wl[(k4 + 0) * WSTRIDE + oc] = rd.x;
    Wl[(k4 + 1) * WSTRIDE + oc] = rd.y;
    Wl[(k4 + 2) * WSTRIDE + oc] = rd.z;
    Wl[(k4 + 3) * WSTRIDE + oc] = rd.w;
  }
  // stage X (shifted, zero-padded)
  for (int i = tid; i < 8192; i += 256) {
    int kk = i >> 6, pos = i & 63;
    int d = pos >> 4, h = (pos >> 2) & 3, w = pos & 3;
    int sd = d + kd, sh = h + kh, sw = w + kw;
    bool ok = ((unsigned)sd < 4u) && ((unsigned)sh < 4u) && ((unsigned)sw < 4u);
    Xl[i] = ok ? dom[((n * 256 + I0 + kk) << 6) + sd * 16 + sh * 4 + sw] : 0.0f;
  }
  __syncthreads();

  int to = tid >> 4, tp = tid & 15;
  f32x4 acc0 = {0, 0, 0, 0}, acc1 = {0, 0, 0, 0}, acc2 = {0, 0, 0, 0}, acc3 = {0, 0, 0, 0};
#pragma unroll 4
  for (int kk = 0; kk < 128; ++kk) {
    f32x4 a = *(f32x4*)&Wl[kk * WSTRIDE + to * 4];
    f32x4 b = *(f32x4*)&Xl[kk * 64 + tp * 4];
    acc0 += a.x * b;
    acc1 += a.y * b;
    acc2 += a.z * b;
    acc3 += a.w * b;
  }
  // P[(tap*2+ich)][n][oc][pos]
  float* pb = P + (size_t)((tap * 2 + ich) * 2 + n) * 8192 + (O0 + to * 4) * 64 + tp * 4;
  *(f32x4*)(pb +   0) = acc0;
  *(f32x4*)(pb +  64) = acc1;
  *(f32x4*)(pb + 128) = acc2;
  *(f32x4*)(pb + 192) = acc3;
}

// ---------------- reduce partials + bias + maxpool2 + relu -> h1[2][128][8] ----------------
// 256 threads: 4 sl-groups x 64 pos (was 64 threads = 1 wave/CU, latency-exposed)
__global__ __launch_bounds__(256) void k_pool1(const float* __restrict__ P,
                                               const float* __restrict__ b1,
                                               float* __restrict__ h1) {
  __shared__ float s[256];
  int n = blockIdx.x >> 7, oc = blockIdx.x & 127;
  int tid = threadIdx.x, pos = tid & 63, sg = tid >> 6;
  float sum = 0.0f;
#pragma unroll
  for (int j = 0; j < 14; ++j) {
    int sl = sg + j * 4;
    if (sl < 54) sum += P[((size_t)(sl * 2 + n) * 128 + oc) * 64 + pos];
  }
  s[tid] = sum;
  __syncthreads();
  if (tid < 64) {
    float tot = b1[oc] + s[pos] + s[64 + pos] + s[128 + pos] + s[192 + pos];
    s[pos] = tot;          // only thread `pos` reads s[pos] afterwards (same wave)
  }
  __syncthreads();
  if (tid < 8) {
    int pd = tid >> 2, ph = (tid >> 1) & 1, pw = tid & 1;
    float m = -3.402823466e38f;
#pragma unroll
    for (int dd = 0; dd < 2; ++dd)
#pragma unroll
      for (int hh = 0; hh < 2; ++hh)
#pragma unroll
        for (int ww = 0; ww < 2; ++ww)
          m = fmaxf(m, s[(pd * 2 + dd) * 16 + (ph * 2 + hh) * 4 + (pw * 2 + ww)]);
    h1[(n * 128 + oc) * 8 + tid] = fmaxf(m, 0.0f);
  }
}

// ---------------- conv2 + bias + maxpool2 + relu + linear (atomic) ----------------
// grid 128 = 2n * 64oc, 64 threads = 8 icgroups x 8 pos
__global__ __launch_bounds__(64) void k_conv2(const float* __restrict__ h1,
                                              const float* __restrict__ w2,
                                              const float* __restrict__ b2,
                                              const float* __restrict__ lw,
                                              const float* __restrict__ lb,
                                              float* __restrict__ logits) {
  __shared__ float hl[1024];    // h1[n][128][8]
  __shared__ float wl[3456];    // w2[oc][128][27]
  __shared__ float red[64];
  int n = blockIdx.x >> 6, oc = blockIdx.x & 63;
  int tid = threadIdx.x;
  for (int i = tid; i < 1024; i += 64) hl[i] = h1[n * 1024 + i];
  for (int i = tid; i < 3456; i += 64) wl[i] = w2[oc * 3456 + i];
  __syncthreads();
  int p = tid & 7, g = tid >> 3;
  int d = p >> 2, h = (p >> 1) & 1, w = p & 1;
  float acc = 0.0f;
  for (int ic = g * 16; ic < g * 16 + 16; ++ic) {
#pragma unroll
    for (int a = 0; a < 2; ++a)
#pragma unroll
      for (int b = 0; b < 2; ++b)
#pragma unroll
        for (int c = 0; c < 2; ++c) {
          int tapi = (a - d + 1) * 9 + (b - h + 1) * 3 + (c - w + 1);
          acc += hl[ic * 8 + a * 4 + b * 2 + c] * wl[ic * 27 + tapi];
        }
  }
  red[tid] = acc;
  __syncthreads();
  if (tid == 0) {
    float mx = -3.402823466e38f;
#pragma unroll
    for (int pp = 0; pp < 8; ++pp) {
      float sv = b2[oc];
#pragma unroll
      for (int gg = 0; gg < 8; ++gg) sv += red[gg * 8 + pp];
      mx = fmaxf(mx, sv);
    }
    float h2v = fmaxf(mx, 0.0f);
    atomicAdd(&logits[n], h2v * lw[oc]);
    if (oc == 0) atomicAdd(&logits[n], lb[0]);
  }
}

extern "C" void kernel_launch(void* const* d_in, const int* in_sizes, int n_in,
                              void* d_out, int out_size, void* d_ws, size_t ws_size,
                              hipStream_t stream) {
  const float* feat  = (const float*)d_in[0];
  const int*   masks = (const int*)  d_in[1];
  const float* dom   = (const float*)d_in[2];
  const float* w1    = (const float*)d_in[3];
  const float* b1    = (const float*)d_in[4];
  const float* w2    = (const float*)d_in[5];
  const float* b2    = (const float*)d_in[6];
  const float* lw    = (const float*)d_in[7];
  const float* lb    = (const float*)d_in[8];
  float* out = (float*)d_out;
  float* ws  = (float*)d_ws;
  float* wt  = ws + WS_WT;
  float* P   = ws + WS_P;
  float* h1  = ws + WS_H1;
  float* logits = out + OUT_LOG;

  k_trans<<<128, 256, 0, stream>>>(w1, wt, logits);
  k_conv1<<<216, 256, 0, stream>>>(dom, wt, P);
  k_pool1<<<256, 256, 0, stream>>>(P, b1, h1);
  k_conv2<<<128, 64, 0, stream>>>(h1, w2, b2, lw, lb, logits);
  k_cam<<<1728, 256, 0, stream>>>(feat, masks, out);
}

// Round 9
// 242.579 us; speedup vs baseline: 1.0110x; 1.0110x over previous
//
#include <hip/hip_runtime.h>

#define VOXELS   884736      // 96^3
#define OUT_CAM  0
#define OUT_PSE  23003136    // 2*13*VOXELS
#define OUT_MSK  24772608
#define OUT_LOG  26542080

// ws layout (floats)
#define WS_WT 0              // wt2[27][128][256]  (884736)
#define WS_P  884736         // P[54][2][128][64]  (884736)
#define WS_H1 1769472        // h1[2][128][8]      (2048)

typedef float  f32x4 __attribute__((ext_vector_type(4)));
typedef int    i32x4 __attribute__((ext_vector_type(4)));

// ---------------- CAM + pseudo + updated masks (memory-bound) ----------------
// Grouped software pipeline: loads of group g+1 are ISSUED BEFORE stores of
// group g, so the vmcnt wait ahead of each compute group covers only its own
// 4 loads -- stores (issued later in vmcnt order) never serialize the chain.
// Round-8 evidence: load->wait->store->load order made each of 28 iterations
// pay load latency + store drain (~5K cy) => 62 us @ 2.5 TB/s.
#define LOADP(reg, k) reg = *(const f32x4*)(feat + (size_t)(n * 14 + 1 + (k)) * VOXELS + v)
#define PROC(reg, k)                                                                   \
  {                                                                                    \
    f32x4 t = reg * scale;                                                             \
    t.x = (t.x > 0.2f) ? t.x : 0.0f;                                                   \
    t.y = (t.y > 0.2f) ? t.y : 0.0f;                                                   \
    t.z = (t.z > 0.2f) ? t.z : 0.0f;                                                   \
    t.w = (t.w > 0.2f) ? t.w : 0.0f;                                                   \
    __builtin_nontemporal_store(t, (f32x4*)(out + OUT_CAM + (size_t)((k) + n * 13) * VOXELS + v)); \
    if ((k) == 0) {                                                                    \
      best = t;                                                                        \
    } else {                                                                           \
      if (t.x > best.x) { best.x = t.x; bi.x = (k); }                                  \
      if (t.y > best.y) { best.y = t.y; bi.y = (k); }                                  \
      if (t.z > best.z) { best.z = t.z; bi.z = (k); }                                  \
      if (t.w > best.w) { best.w = t.w; bi.w = (k); }                                  \
    }                                                                                  \
  }

__global__ __launch_bounds__(256) void k_cam(const float* __restrict__ feat,
                                             const int*   __restrict__ masks,
                                             float* __restrict__ out) {
  int bx = blockIdx.x;                 // 1728 blocks: 864 per n
  int n  = bx >= 864;
  int q  = (bx - n * 864) * 256 + threadIdx.x;   // quad index < 221184
  int v  = q * 4;
  const float scale = 1.0f / 884736.0f;

  f32x4 best = {0, 0, 0, 0};
  i32x4 bi = {0, 0, 0, 0};
  f32x4 a0, a1, a2, a3, b0, b1, b2, b3;

  i32x4 m = *(const i32x4*)(masks + (size_t)n * VOXELS + v);
  LOADP(a0, 0); LOADP(a1, 1); LOADP(a2, 2); LOADP(a3, 3);
  asm volatile("" : "+v"(a0), "+v"(a1), "+v"(a2), "+v"(a3), "+v"(m));

  LOADP(b0, 4); LOADP(b1, 5); LOADP(b2, 6); LOADP(b3, 7);
  asm volatile("" : "+v"(b0), "+v"(b1), "+v"(b2), "+v"(b3));
  PROC(a0, 0); PROC(a1, 1); PROC(a2, 2); PROC(a3, 3);

  LOADP(a0, 8); LOADP(a1, 9); LOADP(a2, 10); LOADP(a3, 11);
  asm volatile("" : "+v"(a0), "+v"(a1), "+v"(a2), "+v"(a3));
  PROC(b0, 4); PROC(b1, 5); PROC(b2, 6); PROC(b3, 7);

  LOADP(b0, 12);
  asm volatile("" : "+v"(b0));
  PROC(a0, 8); PROC(a1, 9); PROC(a2, 10); PROC(a3, 11);

  PROC(b0, 12);

  f32x4 ps = {(float)bi.x, (float)bi.y, (float)bi.z, (float)bi.w};
  f32x4 um;
  um.x = (m.x == 0) ? ps.x : (float)m.x;
  um.y = (m.y == 0) ? ps.y : (float)m.y;
  um.z = (m.z == 0) ? ps.z : (float)m.z;
  um.w = (m.w == 0) ? ps.w : (float)m.w;
  __builtin_nontemporal_store(ps, (f32x4*)(out + OUT_PSE + (size_t)n * VOXELS + v));
  __builtin_nontemporal_store(um, (f32x4*)(out + OUT_MSK + (size_t)n * VOXELS + v));
}

// ---------------- coalesced transpose: wt2[tap][oc][ic] = w1[oc][ic][tap] ----------------
// view w1 as A[r=(oc,ic)][tap]: rows contiguous -> tile = contiguous 6912-float read
// (staged as 1728 float4 loads, ~7 independent per thread). Also zeroes logits.
__global__ __launch_bounds__(256) void k_trans(const float* __restrict__ w1,
                                               float* __restrict__ wt,
                                               float* __restrict__ logits) {
  __shared__ float s[6912];
  int r0 = blockIdx.x * 256;
  int tid = threadIdx.x;
  if (blockIdx.x == 0 && tid < 2) logits[tid] = 0.0f;
  for (int i = tid; i < 1728; i += 256)
    *(f32x4*)&s[i * 4] = *(const f32x4*)&w1[(size_t)r0 * 27 + i * 4];
  __syncthreads();
#pragma unroll
  for (int tap = 0; tap < 27; ++tap)
    wt[tap * 32768 + r0 + tid] = s[tid * 27 + tap];   // stride 27 coprime 32 banks
}

// ---------------- conv1 split-K partial GEMMs ----------------
// grid 216 = 2n * 27tap * 2ich * 2och ; block computes 64oc x 64pos over 128 ic
#define WSTRIDE 68
__global__ __launch_bounds__(256) void k_conv1(const float* __restrict__ dom,
                                               const float* __restrict__ wt,
                                               float* __restrict__ P) {
  __shared__ float Wl[128 * WSTRIDE];   // [kk][oc'] padded: +4 rotates banks
  __shared__ float Xl[128 * 64];        // [kk][pos]
  int bx = blockIdx.x;
  int och = bx & 1;
  int ich = (bx >> 1) & 1;
  int rest = bx >> 2;              // 0..53
  int tap = rest % 27;
  int n = rest / 27;
  int kd = tap / 9 - 1, kh = (tap % 9) / 3 - 1, kw = tap % 3 - 1;
  int I0 = ich * 128, O0 = och * 64;
  int tid = threadIdx.x;

  // stage W: read wt2[tap][oc][ic] coalesced (float4 over ic), transpose into LDS
  for (int i = tid; i < 2048; i += 256) {
    int oc = i >> 5, k4 = (i & 31) << 2;
    f32x4 rd = *(const f32x4*)&wt[(size_t)(tap * 128 + O0 + oc) * 256 + I0 + k4];
    Wl[(k4 + 0) * WSTRIDE + oc] = rd.x;
    Wl[(k4 + 1) * WSTRIDE + oc] = rd.y;
    Wl[(k4 + 2) * WSTRIDE + oc] = rd.z;
    Wl[(k4 + 3) * WSTRIDE + oc] = rd.w;
  }
  // stage X (shifted, zero-padded)
  for (int i = tid; i < 8192; i += 256) {
    int kk = i >> 6, pos = i & 63;
    int d = pos >> 4, h = (pos >> 2) & 3, w = pos & 3;
    int sd = d + kd, sh = h + kh, sw = w + kw;
    bool ok = ((unsigned)sd < 4u) && ((unsigned)sh < 4u) && ((unsigned)sw < 4u);
    Xl[i] = ok ? dom[((n * 256 + I0 + kk) << 6) + sd * 16 + sh * 4 + sw] : 0.0f;
  }
  __syncthreads();

  int to = tid >> 4, tp = tid & 15;
  f32x4 acc0 = {0, 0, 0, 0}, acc1 = {0, 0, 0, 0}, acc2 = {0, 0, 0, 0}, acc3 = {0, 0, 0, 0};
#pragma unroll 4
  for (int kk = 0; kk < 128; ++kk) {
    f32x4 a = *(f32x4*)&Wl[kk * WSTRIDE + to * 4];
    f32x4 b = *(f32x4*)&Xl[kk * 64 + tp * 4];
    acc0 += a.x * b;
    acc1 += a.y * b;
    acc2 += a.z * b;
    acc3 += a.w * b;
  }
  // P[(tap*2+ich)][n][oc][pos]
  float* pb = P + (size_t)((tap * 2 + ich) * 2 + n) * 8192 + (O0 + to * 4) * 64 + tp * 4;
  *(f32x4*)(pb +   0) = acc0;
  *(f32x4*)(pb +  64) = acc1;
  *(f32x4*)(pb + 128) = acc2;
  *(f32x4*)(pb + 192) = acc3;
}

// ---------------- reduce partials + bias + maxpool2 + relu -> h1[2][128][8] ----------------
// 256 threads: 4 sl-groups x 64 pos (was 64 threads = 1 wave/CU, latency-exposed)
__global__ __launch_bounds__(256) void k_pool1(const float* __restrict__ P,
                                               const float* __restrict__ b1,
                                               float* __restrict__ h1) {
  __shared__ float s[256];
  int n = blockIdx.x >> 7, oc = blockIdx.x & 127;
  int tid = threadIdx.x, pos = tid & 63, sg = tid >> 6;
  float sum = 0.0f;
#pragma unroll
  for (int j = 0; j < 14; ++j) {
    int sl = sg + j * 4;
    if (sl < 54) sum += P[((size_t)(sl * 2 + n) * 128 + oc) * 64 + pos];
  }
  s[tid] = sum;
  __syncthreads();
  if (tid < 64) {
    float tot = b1[oc] + s[pos] + s[64 + pos] + s[128 + pos] + s[192 + pos];
    s[pos] = tot;          // only thread `pos` reads s[pos] afterwards (same wave)
  }
  __syncthreads();
  if (tid < 8) {
    int pd = tid >> 2, ph = (tid >> 1) & 1, pw = tid & 1;
    float m = -3.402823466e38f;
#pragma unroll
    for (int dd = 0; dd < 2; ++dd)
#pragma unroll
      for (int hh = 0; hh < 2; ++hh)
#pragma unroll
        for (int ww = 0; ww < 2; ++ww)
          m = fmaxf(m, s[(pd * 2 + dd) * 16 + (ph * 2 + hh) * 4 + (pw * 2 + ww)]);
    h1[(n * 128 + oc) * 8 + tid] = fmaxf(m, 0.0f);
  }
}

// ---------------- conv2 + bias + maxpool2 + relu + linear (atomic) ----------------
// grid 128 = 2n * 64oc, 64 threads = 8 icgroups x 8 pos
__global__ __launch_bounds__(64) void k_conv2(const float* __restrict__ h1,
                                              const float* __restrict__ w2,
                                              const float* __restrict__ b2,
                                              const float* __restrict__ lw,
                                              const float* __restrict__ lb,
                                              float* __restrict__ logits) {
  __shared__ float hl[1024];    // h1[n][128][8]
  __shared__ float wl[3456];    // w2[oc][128][27]
  __shared__ float red[64];
  int n = blockIdx.x >> 6, oc = blockIdx.x & 63;
  int tid = threadIdx.x;
  for (int i = tid; i < 1024; i += 64) hl[i] = h1[n * 1024 + i];
  for (int i = tid; i < 3456; i += 64) wl[i] = w2[oc * 3456 + i];
  __syncthreads();
  int p = tid & 7, g = tid >> 3;
  int d = p >> 2, h = (p >> 1) & 1, w = p & 1;
  float acc = 0.0f;
  for (int ic = g * 16; ic < g * 16 + 16; ++ic) {
#pragma unroll
    for (int a = 0; a < 2; ++a)
#pragma unroll
      for (int b = 0; b < 2; ++b)
#pragma unroll
        for (int c = 0; c < 2; ++c) {
          int tapi = (a - d + 1) * 9 + (b - h + 1) * 3 + (c - w + 1);
          acc += hl[ic * 8 + a * 4 + b * 2 + c] * wl[ic * 27 + tapi];
        }
  }
  red[tid] = acc;
  __syncthreads();
  if (tid == 0) {
    float mx = -3.402823466e38f;
#pragma unroll
    for (int pp = 0; pp < 8; ++pp) {
      float sv = b2[oc];
#pragma unroll
      for (int gg = 0; gg < 8; ++gg) sv += red[gg * 8 + pp];
      mx = fmaxf(mx, sv);
    }
    float h2v = fmaxf(mx, 0.0f);
    atomicAdd(&logits[n], h2v * lw[oc]);
    if (oc == 0) atomicAdd(&logits[n], lb[0]);
  }
}

extern "C" void kernel_launch(void* const* d_in, const int* in_sizes, int n_in,
                              void* d_out, int out_size, void* d_ws, size_t ws_size,
                              hipStream_t stream) {
  const float* feat  = (const float*)d_in[0];
  const int*   masks = (const int*)  d_in[1];
  const float* dom   = (const float*)d_in[2];
  const float* w1    = (const float*)d_in[3];
  const float* b1    = (const float*)d_in[4];
  const float* w2    = (const float*)d_in[5];
  const float* b2    = (const float*)d_in[6];
  const float* lw    = (const float*)d_in[7];
  const float* lb    = (const float*)d_in[8];
  float* out = (float*)d_out;
  float* ws  = (float*)d_ws;
  float* wt  = ws + WS_WT;
  float* P   = ws + WS_P;
  float* h1  = ws + WS_H1;
  float* logits = out + OUT_LOG;

  k_trans<<<128, 256, 0, stream>>>(w1, wt, logits);
  k_conv1<<<216, 256, 0, stream>>>(dom, wt, P);
  k_pool1<<<256, 256, 0, stream>>>(P, b1, h1);
  k_conv2<<<128, 64, 0, stream>>>(h1, w2, b2, lw, lb, logits);
  k_cam<<<1728, 256, 0, stream>>>(feat, masks, out);
}